// Round 8
// baseline (329.401 us; speedup 1.0000x reference)
//
#include <hip/hip_runtime.h>

#define N_NODES 100000
#define N_EDGES 1600000
#define D_IN 256
#define D_OUT 128

#define NPB 128                                   // nodes per bin
#define NB 782                                    // ceil(N_NODES / NPB)
#define REGION 2432                               // bin cap (mean 2046, +8.5 sigma)
#define CHUNK 4096                                // edges per count/flush block
#define NCHUNK 391                                // ceil(N_EDGES / CHUNK)
#define GEMM_BLOCKS 782                           // 128 rows per block (8 waves x 16)

typedef __attribute__((ext_vector_type(8))) short bf16x8;
typedef __attribute__((ext_vector_type(4))) float f32x4;

__device__ __forceinline__ unsigned short f2bf(float f) {
    unsigned u = __float_as_uint(f);
    u += 0x7FFF + ((u >> 16) & 1);          // round-to-nearest-even
    return (unsigned short)(u >> 16);
}
__device__ __forceinline__ float bflo(unsigned p) { return __uint_as_float(p << 16); }
__device__ __forceinline__ float bfhi(unsigned p) { return __uint_as_float(p & 0xFFFF0000u); }

// ---------------------------------------------------------------------------
// prep: W[256][128] f32 -> Wt[128][256] bf16 (col-major). Nothing else needs
// zero-init anymore (counts/starts/totals are fully written each launch).
// ---------------------------------------------------------------------------
__global__ void prep_kernel(const float* __restrict__ W,
                            unsigned short* __restrict__ Wt) {
    int idx = blockIdx.x * 256 + threadIdx.x;      // grid covers 32768
    if (idx < D_OUT * D_IN) {
        int c = idx >> 8;
        int k = idx & 255;
        Wt[idx] = f2bf(W[(size_t)k * D_OUT + c]);
    }
}

// ---------------------------------------------------------------------------
// fusedA: blockIdx < NCHUNK -> count (LDS histogram -> counts[block][bin],
//         coalesced stores, NO atomics, NO scan, NO staging)
//         else              -> gemm (bf16 MFMA, 128 rows per block)
// ---------------------------------------------------------------------------
struct CountSmem { int hist[NB]; };                 //  3,128 B
struct GemmSmem { unsigned short tile[8][16 * 136]; };   // 34,816 B
union FusedSmem { CountSmem c; GemmSmem g; };

__global__ __launch_bounds__(512) void fusedA_kernel(
        const float* __restrict__ x,
        const unsigned short* __restrict__ Wt,
        unsigned short* __restrict__ supb,
        const int* __restrict__ dst,
        int* __restrict__ counts) {
    __shared__ FusedSmem sm;
    int tid = threadIdx.x;

    if (blockIdx.x < NCHUNK) {
        // ------------------------------ count -----------------------------
        int* hist = sm.c.hist;
        int e0 = blockIdx.x * CHUNK;
        for (int i = tid; i < NB; i += 512) hist[i] = 0;
        __syncthreads();
#pragma unroll
        for (int k = 0; k < 8; ++k) {
            int e = e0 + k * 512 + tid;
            if (e < N_EDGES) atomicAdd(&hist[dst[e] >> 7], 1);
        }
        __syncthreads();
        int* crow = counts + (size_t)blockIdx.x * NB;
        for (int i = tid; i < NB; i += 512) crow[i] = hist[i];
    } else {
        // ------------------------------ gemm ------------------------------
        GemmSmem& gs = sm.g;
        int gb = blockIdx.x - NCHUNK;
        int widl = tid >> 6;                  // 0..7
        int lane = tid & 63;
        int r0 = (gb * 8 + widl) * 16;
        int rowA = r0 + (lane & 15);
        int rowAc = rowA < N_NODES ? rowA : N_NODES - 1;
        int kgrp = (lane >> 4) * 8;           // 0,8,16,24

        f32x4 acc[8];
#pragma unroll
        for (int t = 0; t < 8; ++t) acc[t] = (f32x4){0.f, 0.f, 0.f, 0.f};

        const float* xrow = x + (size_t)rowAc * D_IN + kgrp;
        int colbase = lane & 15;

#pragma unroll
        for (int ks = 0; ks < 8; ++ks) {
            int k0 = ks * 32;
            float4 a0 = *(const float4*)(xrow + k0);
            float4 a1 = *(const float4*)(xrow + k0 + 4);
            bf16x8 afrag;
            afrag[0] = (short)f2bf(a0.x); afrag[1] = (short)f2bf(a0.y);
            afrag[2] = (short)f2bf(a0.z); afrag[3] = (short)f2bf(a0.w);
            afrag[4] = (short)f2bf(a1.x); afrag[5] = (short)f2bf(a1.y);
            afrag[6] = (short)f2bf(a1.z); afrag[7] = (short)f2bf(a1.w);
#pragma unroll
            for (int t = 0; t < 8; ++t) {
                bf16x8 bfrag = *(const bf16x8*)(Wt +
                        (size_t)(t * 16 + colbase) * D_IN + k0 + kgrp);
                acc[t] = __builtin_amdgcn_mfma_f32_16x16x32_bf16(afrag, bfrag,
                                                                 acc[t], 0, 0, 0);
            }
        }

        // epilogue: acc -> per-wave LDS tile (no barrier) -> 16B stores
        unsigned short* tl = gs.tile[widl];
        int rgrp = (lane >> 4) * 4;
#pragma unroll
        for (int t = 0; t < 8; ++t)
#pragma unroll
            for (int j = 0; j < 4; ++j)
                tl[(rgrp + j) * 136 + t * 16 + colbase] = f2bf(acc[t][j]);

        int row = lane >> 2;
        int c4 = lane & 3;
        int orow = r0 + row;
        if (orow < N_NODES) {
#pragma unroll
            for (int u = 0; u < 4; ++u) {
                int col0 = u * 32 + c4 * 8;
                int4 v = *(const int4*)(tl + row * 136 + col0);
                *(int4*)(supb + (size_t)orow * D_OUT + col0) = v;
            }
        }
    }
}

// ---------------------------------------------------------------------------
// scanB: per bin, exclusive prefix over the 391 block-counts.
// One wave per bin (8 bins per 512-thr block). No barriers, no atomics.
// starts[block][bin] = offset of that block's run inside the bin region;
// totals[bin] = bin's edge count.
// ---------------------------------------------------------------------------
__global__ __launch_bounds__(512) void scanB_kernel(
        const int* __restrict__ counts,
        int* __restrict__ starts,
        int* __restrict__ totals) {
    int wv = threadIdx.x >> 6, lane = threadIdx.x & 63;
    int bin = blockIdx.x * 8 + wv;
    if (bin >= NB) return;
    int carry = 0;
#pragma unroll
    for (int g = 0; g < 7; ++g) {               // ceil(391/64) = 7
        int idx = g * 64 + lane;                // block index
        int v = (idx < NCHUNK) ? counts[(size_t)idx * NB + bin] : 0;
        int s = v;
#pragma unroll
        for (int d = 1; d < 64; d <<= 1) {
            int u = __shfl_up(s, d, 64);
            if (lane >= d) s += u;
        }
        if (idx < NCHUNK) starts[(size_t)idx * NB + bin] = carry + s - v;
        carry += __shfl(s, 63, 64);
    }
    if (lane == 0) totals[bin] = carry;
}

// ---------------------------------------------------------------------------
// flushC: reload edges, seed LDS cursors with global per-(block,bin) starts,
// direct-store tuples to stg. Unique slots -> ZERO global atomics; each
// block's per-bin run is contiguous (line sharing only at run boundaries).
// Tuple: {src | dloc<<17, w_bits}, dloc = dst & 127.
// ---------------------------------------------------------------------------
__global__ __launch_bounds__(512) void flushC_kernel(
        const int* __restrict__ src,
        const int* __restrict__ dst,
        const float* __restrict__ ew,
        const int* __restrict__ starts,
        int2* __restrict__ stg) {
    __shared__ int cur[NB];
    int tid = threadIdx.x;
    int e0 = blockIdx.x * CHUNK;

    const int* srow = starts + (size_t)blockIdx.x * NB;
    for (int i = tid; i < NB; i += 512) cur[i] = srow[i];
    __syncthreads();

#pragma unroll
    for (int k = 0; k < 8; ++k) {
        int e = e0 + k * 512 + tid;
        if (e < N_EDGES) {
            int d = dst[e];
            int bin = d >> 7;
            int pos = atomicAdd(&cur[bin], 1);
            if (pos < REGION)
                stg[(size_t)bin * REGION + pos] =
                    make_int2(src[e] | ((d & 127) << 17), __float_as_int(ew[e]));
        }
    }
}

// ---------------------------------------------------------------------------
// sgather: one block (512 thr) per 128-node bin (782 blocks).
//  A: stash tuples in regs + histogram dloc (128 keys)
//  B: exclusive scan -> base/cursor
//  C: scatter from regs into sorted[] (node-grouped, LDS)
//  D: 8 waves x 16 nodes, register accumulate (lane = 2 ch), 4x unroll.
// ---------------------------------------------------------------------------
__global__ __launch_bounds__(512) void sgather_kernel(
        const unsigned short* __restrict__ supb,
        const int2* __restrict__ stg,
        const int* __restrict__ totals,
        const float* __restrict__ b,
        float* __restrict__ out) {
    __shared__ int2 sorted[REGION];          // 19,456 B
    __shared__ int hist2[NPB];
    __shared__ int base2[NPB + 1];
    __shared__ int cur2[NPB];
    __shared__ int scanbuf[512];

    int tid = threadIdx.x;
    int bkt = blockIdx.x;
    int node0 = bkt * NPB;

    if (tid < NPB) hist2[tid] = 0;
    __syncthreads();

    int cnt = totals[bkt];
    if (cnt > REGION) cnt = REGION;
    const int2* sg = stg + (size_t)bkt * REGION;

    int2 tp[5];
    int dl[5];
#pragma unroll
    for (int k = 0; k < 5; ++k) {
        int e = tid + k * 512;
        dl[k] = -1;
        if (e < cnt) {
            tp[k] = sg[e];
            dl[k] = (tp[k].x >> 17) & 127;
            atomicAdd(&hist2[dl[k]], 1);
        }
    }
    __syncthreads();

    int v = (tid < NPB) ? hist2[tid] : 0;
    scanbuf[tid] = v;
    __syncthreads();
    for (int d = 1; d < NPB; d <<= 1) {
        int t = (tid >= d) ? scanbuf[tid - d] : 0;
        __syncthreads();
        scanbuf[tid] += t;
        __syncthreads();
    }
    if (tid < NPB) {
        base2[tid] = scanbuf[tid] - v;
        cur2[tid] = scanbuf[tid] - v;
    }
    if (tid == 0) base2[NPB] = cnt;
    __syncthreads();

#pragma unroll
    for (int k = 0; k < 5; ++k) {
        if (dl[k] >= 0) {
            int pos = atomicAdd(&cur2[dl[k]], 1);
            sorted[pos] = tp[k];
        }
    }
    __syncthreads();

    int wave = tid >> 6, lane = tid & 63;
    float2 bv = ((const float2*)b)[lane];

#pragma unroll 1
    for (int jj = 0; jj < 16; ++jj) {
        int j = wave * 16 + jj;
        int node = node0 + j;
        if (node >= N_NODES) break;
        int s = base2[j], t = base2[j + 1];
        float ax = 0.f, ay = 0.f;
        int e = s;
        for (; e + 3 < t; e += 4) {
            int2 t0 = sorted[e];
            int2 t1 = sorted[e + 1];
            int2 t2 = sorted[e + 2];
            int2 t3 = sorted[e + 3];
            unsigned p0 = *(const unsigned*)(supb + (size_t)(t0.x & 0x1FFFF) * D_OUT + 2 * lane);
            unsigned p1 = *(const unsigned*)(supb + (size_t)(t1.x & 0x1FFFF) * D_OUT + 2 * lane);
            unsigned p2 = *(const unsigned*)(supb + (size_t)(t2.x & 0x1FFFF) * D_OUT + 2 * lane);
            unsigned p3 = *(const unsigned*)(supb + (size_t)(t3.x & 0x1FFFF) * D_OUT + 2 * lane);
            float w0 = __int_as_float(t0.y);
            float w1 = __int_as_float(t1.y);
            float w2 = __int_as_float(t2.y);
            float w3 = __int_as_float(t3.y);
            ax += w0 * bflo(p0) + w1 * bflo(p1) + w2 * bflo(p2) + w3 * bflo(p3);
            ay += w0 * bfhi(p0) + w1 * bfhi(p1) + w2 * bfhi(p2) + w3 * bfhi(p3);
        }
        for (; e < t; ++e) {
            int2 t0 = sorted[e];
            unsigned p0 = *(const unsigned*)(supb + (size_t)(t0.x & 0x1FFFF) * D_OUT + 2 * lane);
            float w0 = __int_as_float(t0.y);
            ax += w0 * bflo(p0);
            ay += w0 * bfhi(p0);
        }
        ((float2*)(out + (size_t)node * D_OUT))[lane] =
            make_float2(ax + bv.x, ay + bv.y);
    }
}

// ---------------------------------------------------------------------------
extern "C" void kernel_launch(void* const* d_in, const int* in_sizes, int n_in,
                              void* d_out, int out_size, void* d_ws, size_t ws_size,
                              hipStream_t stream) {
    const float* x   = (const float*)d_in[0];
    const int* esrc  = (const int*)d_in[1];
    const int* edst  = (const int*)d_in[2];
    const float* ew  = (const float*)d_in[3];
    const float* W   = (const float*)d_in[4];
    const float* b   = (const float*)d_in[5];
    float* out = (float*)d_out;

    // workspace layout (~43.4 MB)
    uint8_t* w8 = (uint8_t*)d_ws;
    unsigned short* supb = (unsigned short*)w8;               // 25,600,000 B
    int2* stg    = (int2*)(w8 + 25600000);                    // 15,214,592 B (782*2432*8)
    int* counts  = (int*)(w8 + 40814592);                     //  1,223,048 B (391*782*4)
    int* starts  = (int*)(w8 + 42037640);                     //  1,223,048 B
    int* totals  = (int*)(w8 + 43260688);                     //      3,128 B
    unsigned short* Wt = (unsigned short*)(w8 + 43264000);    //     65,536 B

    prep_kernel<<<(D_OUT * D_IN + 255) / 256, 256, 0, stream>>>(W, Wt);

    fusedA_kernel<<<NCHUNK + GEMM_BLOCKS, 512, 0, stream>>>(
        x, Wt, supb, edst, counts);

    scanB_kernel<<<(NB + 7) / 8, 512, 0, stream>>>(counts, starts, totals);

    flushC_kernel<<<NCHUNK, 512, 0, stream>>>(esrc, edst, ew, starts, stg);

    sgather_kernel<<<NB, 512, 0, stream>>>(supb, stg, totals, b, out);
}

// Round 9
// 314.680 us; speedup vs baseline: 1.0468x; 1.0468x over previous
//
#include <hip/hip_runtime.h>

#define N_NODES 100000
#define N_EDGES 1600000
#define D_IN 256
#define D_OUT 128

#define NPB 128                                   // nodes per bin
#define NB 782                                    // ceil(N_NODES / NPB)
#define REGION 2432                               // bin cap (mean 2046, +8.5 sigma)
#define CHUNK 4096                                // edges per count/flush block
#define NCHUNK 391                                // ceil(N_EDGES / CHUNK)
#define GEMM_BLOCKS 782                           // 128 rows per block (4 waves x 32)

typedef __attribute__((ext_vector_type(8))) short bf16x8;
typedef __attribute__((ext_vector_type(4))) float f32x4;

__device__ __forceinline__ unsigned short f2bf(float f) {
    unsigned u = __float_as_uint(f);
    u += 0x7FFF + ((u >> 16) & 1);          // round-to-nearest-even
    return (unsigned short)(u >> 16);
}
__device__ __forceinline__ float bflo(unsigned p) { return __uint_as_float(p << 16); }
__device__ __forceinline__ float bfhi(unsigned p) { return __uint_as_float(p & 0xFFFF0000u); }

// ---------------------------------------------------------------------------
// prep: W[256][128] f32 -> Wt[128][256] bf16 (col-major)
// ---------------------------------------------------------------------------
__global__ void prep_kernel(const float* __restrict__ W,
                            unsigned short* __restrict__ Wt) {
    int idx = blockIdx.x * 256 + threadIdx.x;      // grid covers 32768
    if (idx < D_OUT * D_IN) {
        int c = idx >> 8;
        int k = idx & 255;
        Wt[idx] = f2bf(W[(size_t)k * D_OUT + c]);
    }
}

// ---------------------------------------------------------------------------
// fusedA: blockIdx < NCHUNK -> count (LDS histogram -> counts[block][bin])
//         else              -> gemm (bf16 MFMA, 32 rows/wave: two 16-row
//         A-tiles share every B-fragment -> 2:1 MFMA:load, half Wt traffic)
// 256 threads; LDS union 17.4 KB; __launch_bounds__(256,4) caps VGPR at 128
// -> 4 blocks/CU.
// ---------------------------------------------------------------------------
struct CountSmem { int hist[NB]; };                        //  3,128 B
struct GemmSmem { unsigned short tile[4][16 * 136]; };     // 17,408 B
union FusedSmem { CountSmem c; GemmSmem g; };

__global__ __launch_bounds__(256, 4) void fusedA_kernel(
        const float* __restrict__ x,
        const unsigned short* __restrict__ Wt,
        unsigned short* __restrict__ supb,
        const int* __restrict__ dst,
        int* __restrict__ counts) {
    __shared__ FusedSmem sm;
    int tid = threadIdx.x;

    if (blockIdx.x < NCHUNK) {
        // ------------------------------ count -----------------------------
        int* hist = sm.c.hist;
        int e0 = blockIdx.x * CHUNK;
        for (int i = tid; i < NB; i += 256) hist[i] = 0;
        __syncthreads();
#pragma unroll
        for (int k = 0; k < 16; ++k) {
            int e = e0 + k * 256 + tid;
            if (e < N_EDGES) atomicAdd(&hist[dst[e] >> 7], 1);
        }
        __syncthreads();
        int* crow = counts + (size_t)blockIdx.x * NB;
        for (int i = tid; i < NB; i += 256) crow[i] = hist[i];
    } else {
        // ------------------------------ gemm ------------------------------
        int gb = blockIdx.x - NCHUNK;
        int w = tid >> 6;                     // 0..3
        int lane = tid & 63;
        int r0 = (gb * 4 + w) * 32;           // 32 rows per wave
        int rowA0 = r0 + (lane & 15);
        int rowA1 = rowA0 + 16;
        int rowA0c = rowA0 < N_NODES ? rowA0 : N_NODES - 1;
        int rowA1c = rowA1 < N_NODES ? rowA1 : N_NODES - 1;
        int kgrp = (lane >> 4) * 8;           // 0,8,16,24

        f32x4 acc0[8], acc1[8];
#pragma unroll
        for (int t = 0; t < 8; ++t) {
            acc0[t] = (f32x4){0.f, 0.f, 0.f, 0.f};
            acc1[t] = (f32x4){0.f, 0.f, 0.f, 0.f};
        }

        const float* xr0 = x + (size_t)rowA0c * D_IN + kgrp;
        const float* xr1 = x + (size_t)rowA1c * D_IN + kgrp;
        int colbase = lane & 15;

#pragma unroll
        for (int ks = 0; ks < 8; ++ks) {
            int k0 = ks * 32;
            float4 a0 = *(const float4*)(xr0 + k0);
            float4 a1 = *(const float4*)(xr0 + k0 + 4);
            float4 c0 = *(const float4*)(xr1 + k0);
            float4 c1 = *(const float4*)(xr1 + k0 + 4);
            bf16x8 af0, af1;
            af0[0] = (short)f2bf(a0.x); af0[1] = (short)f2bf(a0.y);
            af0[2] = (short)f2bf(a0.z); af0[3] = (short)f2bf(a0.w);
            af0[4] = (short)f2bf(a1.x); af0[5] = (short)f2bf(a1.y);
            af0[6] = (short)f2bf(a1.z); af0[7] = (short)f2bf(a1.w);
            af1[0] = (short)f2bf(c0.x); af1[1] = (short)f2bf(c0.y);
            af1[2] = (short)f2bf(c0.z); af1[3] = (short)f2bf(c0.w);
            af1[4] = (short)f2bf(c1.x); af1[5] = (short)f2bf(c1.y);
            af1[6] = (short)f2bf(c1.z); af1[7] = (short)f2bf(c1.w);
#pragma unroll
            for (int t = 0; t < 8; ++t) {
                bf16x8 bfrag = *(const bf16x8*)(Wt +
                        (size_t)(t * 16 + colbase) * D_IN + k0 + kgrp);
                acc0[t] = __builtin_amdgcn_mfma_f32_16x16x32_bf16(af0, bfrag,
                                                                  acc0[t], 0, 0, 0);
                acc1[t] = __builtin_amdgcn_mfma_f32_16x16x32_bf16(af1, bfrag,
                                                                  acc1[t], 0, 0, 0);
            }
        }

        // epilogue: two row-tiles through the per-wave LDS buffer (no barrier)
        unsigned short* tl = sm.g.tile[w];
        int rgrp = (lane >> 4) * 4;
        int row = lane >> 2;
        int c4 = lane & 3;
#pragma unroll
        for (int tilei = 0; tilei < 2; ++tilei) {
            const f32x4* ac = tilei ? acc1 : acc0;
#pragma unroll
            for (int t = 0; t < 8; ++t)
#pragma unroll
                for (int j = 0; j < 4; ++j)
                    tl[(rgrp + j) * 136 + t * 16 + colbase] = f2bf(ac[t][j]);

            int orow = r0 + tilei * 16 + row;
            if (orow < N_NODES) {
#pragma unroll
                for (int u = 0; u < 4; ++u) {
                    int col0 = u * 32 + c4 * 8;
                    int4 v = *(const int4*)(tl + row * 136 + col0);
                    *(int4*)(supb + (size_t)orow * D_OUT + col0) = v;
                }
            }
        }
    }
}

// ---------------------------------------------------------------------------
// scanB: per bin, exclusive prefix over the 391 block-counts.
// One wave per bin (8 bins per 512-thr block). No barriers, no atomics.
// ---------------------------------------------------------------------------
__global__ __launch_bounds__(512) void scanB_kernel(
        const int* __restrict__ counts,
        int* __restrict__ starts,
        int* __restrict__ totals) {
    int wv = threadIdx.x >> 6, lane = threadIdx.x & 63;
    int bin = blockIdx.x * 8 + wv;
    if (bin >= NB) return;
    int carry = 0;
#pragma unroll
    for (int g = 0; g < 7; ++g) {               // ceil(391/64) = 7
        int idx = g * 64 + lane;                // block index
        int v = (idx < NCHUNK) ? counts[(size_t)idx * NB + bin] : 0;
        int s = v;
#pragma unroll
        for (int d = 1; d < 64; d <<= 1) {
            int u = __shfl_up(s, d, 64);
            if (lane >= d) s += u;
        }
        if (idx < NCHUNK) starts[(size_t)idx * NB + bin] = carry + s - v;
        carry += __shfl(s, 63, 64);
    }
    if (lane == 0) totals[bin] = carry;
}

// ---------------------------------------------------------------------------
// flushC: reload edges, seed LDS cursors with global per-(block,bin) starts,
// direct-store tuples to stg. Unique slots -> zero global atomics.
// Tuple: {src | dloc<<17, w_bits}, dloc = dst & 127.
// ---------------------------------------------------------------------------
__global__ __launch_bounds__(512) void flushC_kernel(
        const int* __restrict__ src,
        const int* __restrict__ dst,
        const float* __restrict__ ew,
        const int* __restrict__ starts,
        int2* __restrict__ stg) {
    __shared__ int cur[NB];
    int tid = threadIdx.x;
    int e0 = blockIdx.x * CHUNK;

    const int* srow = starts + (size_t)blockIdx.x * NB;
    for (int i = tid; i < NB; i += 512) cur[i] = srow[i];
    __syncthreads();

#pragma unroll
    for (int k = 0; k < 8; ++k) {
        int e = e0 + k * 512 + tid;
        if (e < N_EDGES) {
            int d = dst[e];
            int bin = d >> 7;
            int pos = atomicAdd(&cur[bin], 1);
            if (pos < REGION)
                stg[(size_t)bin * REGION + pos] =
                    make_int2(src[e] | ((d & 127) << 17), __float_as_int(ew[e]));
        }
    }
}

// ---------------------------------------------------------------------------
// sgather: one block (512 thr) per 128-node bin (782 blocks).
//  A: stash tuples in regs + histogram dloc (128 keys)
//  B: exclusive scan -> base/cursor
//  C: scatter from regs into sorted[] (node-grouped, LDS)
//  D: 8 waves x 16 nodes, register accumulate (lane = 2 ch), 4x unroll.
// ---------------------------------------------------------------------------
__global__ __launch_bounds__(512) void sgather_kernel(
        const unsigned short* __restrict__ supb,
        const int2* __restrict__ stg,
        const int* __restrict__ totals,
        const float* __restrict__ b,
        float* __restrict__ out) {
    __shared__ int2 sorted[REGION];          // 19,456 B
    __shared__ int hist2[NPB];
    __shared__ int base2[NPB + 1];
    __shared__ int cur2[NPB];
    __shared__ int scanbuf[512];

    int tid = threadIdx.x;
    int bkt = blockIdx.x;
    int node0 = bkt * NPB;

    if (tid < NPB) hist2[tid] = 0;
    __syncthreads();

    int cnt = totals[bkt];
    if (cnt > REGION) cnt = REGION;
    const int2* sg = stg + (size_t)bkt * REGION;

    int2 tp[5];
    int dl[5];
#pragma unroll
    for (int k = 0; k < 5; ++k) {
        int e = tid + k * 512;
        dl[k] = -1;
        if (e < cnt) {
            tp[k] = sg[e];
            dl[k] = (tp[k].x >> 17) & 127;
            atomicAdd(&hist2[dl[k]], 1);
        }
    }
    __syncthreads();

    int v = (tid < NPB) ? hist2[tid] : 0;
    scanbuf[tid] = v;
    __syncthreads();
    for (int d = 1; d < NPB; d <<= 1) {
        int t = (tid >= d) ? scanbuf[tid - d] : 0;
        __syncthreads();
        scanbuf[tid] += t;
        __syncthreads();
    }
    if (tid < NPB) {
        base2[tid] = scanbuf[tid] - v;
        cur2[tid] = scanbuf[tid] - v;
    }
    if (tid == 0) base2[NPB] = cnt;
    __syncthreads();

#pragma unroll
    for (int k = 0; k < 5; ++k) {
        if (dl[k] >= 0) {
            int pos = atomicAdd(&cur2[dl[k]], 1);
            sorted[pos] = tp[k];
        }
    }
    __syncthreads();

    int wave = tid >> 6, lane = tid & 63;
    float2 bv = ((const float2*)b)[lane];

#pragma unroll 1
    for (int jj = 0; jj < 16; ++jj) {
        int j = wave * 16 + jj;
        int node = node0 + j;
        if (node >= N_NODES) break;
        int s = base2[j], t = base2[j + 1];
        float ax = 0.f, ay = 0.f;
        int e = s;
        for (; e + 3 < t; e += 4) {
            int2 t0 = sorted[e];
            int2 t1 = sorted[e + 1];
            int2 t2 = sorted[e + 2];
            int2 t3 = sorted[e + 3];
            unsigned p0 = *(const unsigned*)(supb + (size_t)(t0.x & 0x1FFFF) * D_OUT + 2 * lane);
            unsigned p1 = *(const unsigned*)(supb + (size_t)(t1.x & 0x1FFFF) * D_OUT + 2 * lane);
            unsigned p2 = *(const unsigned*)(supb + (size_t)(t2.x & 0x1FFFF) * D_OUT + 2 * lane);
            unsigned p3 = *(const unsigned*)(supb + (size_t)(t3.x & 0x1FFFF) * D_OUT + 2 * lane);
            float w0 = __int_as_float(t0.y);
            float w1 = __int_as_float(t1.y);
            float w2 = __int_as_float(t2.y);
            float w3 = __int_as_float(t3.y);
            ax += w0 * bflo(p0) + w1 * bflo(p1) + w2 * bflo(p2) + w3 * bflo(p3);
            ay += w0 * bfhi(p0) + w1 * bfhi(p1) + w2 * bfhi(p2) + w3 * bfhi(p3);
        }
        for (; e < t; ++e) {
            int2 t0 = sorted[e];
            unsigned p0 = *(const unsigned*)(supb + (size_t)(t0.x & 0x1FFFF) * D_OUT + 2 * lane);
            float w0 = __int_as_float(t0.y);
            ax += w0 * bflo(p0);
            ay += w0 * bfhi(p0);
        }
        ((float2*)(out + (size_t)node * D_OUT))[lane] =
            make_float2(ax + bv.x, ay + bv.y);
    }
}

// ---------------------------------------------------------------------------
extern "C" void kernel_launch(void* const* d_in, const int* in_sizes, int n_in,
                              void* d_out, int out_size, void* d_ws, size_t ws_size,
                              hipStream_t stream) {
    const float* x   = (const float*)d_in[0];
    const int* esrc  = (const int*)d_in[1];
    const int* edst  = (const int*)d_in[2];
    const float* ew  = (const float*)d_in[3];
    const float* W   = (const float*)d_in[4];
    const float* b   = (const float*)d_in[5];
    float* out = (float*)d_out;

    // workspace layout (~43.4 MB)
    uint8_t* w8 = (uint8_t*)d_ws;
    unsigned short* supb = (unsigned short*)w8;               // 25,600,000 B
    int2* stg    = (int2*)(w8 + 25600000);                    // 15,214,592 B (782*2432*8)
    int* counts  = (int*)(w8 + 40814592);                     //  1,223,048 B (391*782*4)
    int* starts  = (int*)(w8 + 42037640);                     //  1,223,048 B
    int* totals  = (int*)(w8 + 43260688);                     //      3,128 B
    unsigned short* Wt = (unsigned short*)(w8 + 43264000);    //     65,536 B

    prep_kernel<<<(D_OUT * D_IN + 255) / 256, 256, 0, stream>>>(W, Wt);

    fusedA_kernel<<<NCHUNK + GEMM_BLOCKS, 256, 0, stream>>>(
        x, Wt, supb, edst, counts);

    scanB_kernel<<<(NB + 7) / 8, 512, 0, stream>>>(counts, starts, totals);

    flushC_kernel<<<NCHUNK, 512, 0, stream>>>(esrc, edst, ew, starts, stg);

    sgather_kernel<<<NB, 512, 0, stream>>>(supb, stg, totals, b, out);
}

// Round 10
// 302.501 us; speedup vs baseline: 1.0889x; 1.0403x over previous
//
#include <hip/hip_runtime.h>

#define N_NODES 100000
#define N_EDGES 1600000
#define D_IN 256
#define D_OUT 128

#define NPB 128                                   // nodes per bin
#define NB 782                                    // ceil(N_NODES / NPB)
#define REGION 2432                               // bin cap (mean 2046, +8.5 sigma)
#define CHUNK 4096                                // edges per count/flush block
#define NCHUNK 391                                // ceil(N_EDGES / CHUNK)
#define GEMM_BLOCKS 782                           // 128 rows per block (4 waves x 32)

typedef __attribute__((ext_vector_type(8))) short bf16x8;
typedef __attribute__((ext_vector_type(4))) float f32x4;

__device__ __forceinline__ unsigned short f2bf(float f) {
    unsigned u = __float_as_uint(f);
    u += 0x7FFF + ((u >> 16) & 1);          // round-to-nearest-even
    return (unsigned short)(u >> 16);
}
__device__ __forceinline__ float bflo(unsigned p) { return __uint_as_float(p << 16); }
__device__ __forceinline__ float bfhi(unsigned p) { return __uint_as_float(p & 0xFFFF0000u); }

// ---------------------------------------------------------------------------
// prep: W[256][128] f32 -> Wt[128][256] bf16 (col-major)
// ---------------------------------------------------------------------------
__global__ void prep_kernel(const float* __restrict__ W,
                            unsigned short* __restrict__ Wt) {
    int idx = blockIdx.x * 256 + threadIdx.x;      // grid covers 32768
    if (idx < D_OUT * D_IN) {
        int c = idx >> 8;
        int k = idx & 255;
        Wt[idx] = f2bf(W[(size_t)k * D_OUT + c]);
    }
}

// ---------------------------------------------------------------------------
// fusedA: blockIdx < NCHUNK -> count (LDS histogram -> counts[block][bin])
//         else              -> gemm: Wt staged in LDS (64 KB, XOR-swizzled
//         byte ^= (col&7)<<4 to break the 512B-stride same-bank pattern),
//         B-fragments via ds_read_b128, 32 rows/wave. Epilogue reuses the
//         Wt LDS region after a barrier (Wt dead post-compute). 64 KB total,
//         2 blocks/CU; VGPR free to 256 (2 waves/SIMD) for deep x prefetch.
// ---------------------------------------------------------------------------
union FusedSmem {
    int hist[NB];                       //  3,128 B (count blocks)
    unsigned short wt[128 * 256];       // 65,536 B (gemm: Wt, then epilogue tiles)
};

__global__ __launch_bounds__(256) void fusedA_kernel(
        const float* __restrict__ x,
        const unsigned short* __restrict__ Wt,
        unsigned short* __restrict__ supb,
        const int* __restrict__ dst,
        int* __restrict__ counts) {
    __shared__ FusedSmem sm;
    int tid = threadIdx.x;

    if (blockIdx.x < NCHUNK) {
        // ------------------------------ count -----------------------------
        int* hist = sm.hist;
        int e0 = blockIdx.x * CHUNK;
        for (int i = tid; i < NB; i += 256) hist[i] = 0;
        __syncthreads();
#pragma unroll
        for (int k = 0; k < 16; ++k) {
            int e = e0 + k * 256 + tid;
            if (e < N_EDGES) atomicAdd(&hist[dst[e] >> 7], 1);
        }
        __syncthreads();
        int* crow = counts + (size_t)blockIdx.x * NB;
        for (int i = tid; i < NB; i += 256) crow[i] = hist[i];
    } else {
        // ------------------------------ gemm ------------------------------
        // stage Wt -> LDS with XOR swizzle (write 16B chunks)
        {
            const int4* wg = (const int4*)Wt;       // 4096 x 16B
            char* wl = (char*)sm.wt;
            for (int i = tid; i < 4096; i += 256) {
                int off = i * 16;
                int col = off >> 9;                  // byte 512 per col row
                int soff = off ^ ((col & 7) << 4);
                *(int4*)(wl + soff) = wg[i];
            }
        }
        __syncthreads();

        int gb = blockIdx.x - NCHUNK;
        int w = tid >> 6;                     // 0..3
        int lane = tid & 63;
        int r0 = (gb * 4 + w) * 32;           // 32 rows per wave
        int rowA0 = r0 + (lane & 15);
        int rowA1 = rowA0 + 16;
        int rowA0c = rowA0 < N_NODES ? rowA0 : N_NODES - 1;
        int rowA1c = rowA1 < N_NODES ? rowA1 : N_NODES - 1;
        int kgrp = (lane >> 4) * 8;           // 0,8,16,24

        f32x4 acc0[8], acc1[8];
#pragma unroll
        for (int t = 0; t < 8; ++t) {
            acc0[t] = (f32x4){0.f, 0.f, 0.f, 0.f};
            acc1[t] = (f32x4){0.f, 0.f, 0.f, 0.f};
        }

        const float* xr0 = x + (size_t)rowA0c * D_IN + kgrp;
        const float* xr1 = x + (size_t)rowA1c * D_IN + kgrp;
        int colbase = lane & 15;
        const char* wl = (const char*)sm.wt;

#pragma unroll
        for (int ks = 0; ks < 8; ++ks) {
            int k0 = ks * 32;
            float4 a0 = *(const float4*)(xr0 + k0);
            float4 a1 = *(const float4*)(xr0 + k0 + 4);
            float4 c0 = *(const float4*)(xr1 + k0);
            float4 c1 = *(const float4*)(xr1 + k0 + 4);
            bf16x8 af0, af1;
            af0[0] = (short)f2bf(a0.x); af0[1] = (short)f2bf(a0.y);
            af0[2] = (short)f2bf(a0.z); af0[3] = (short)f2bf(a0.w);
            af0[4] = (short)f2bf(a1.x); af0[5] = (short)f2bf(a1.y);
            af0[6] = (short)f2bf(a1.z); af0[7] = (short)f2bf(a1.w);
            af1[0] = (short)f2bf(c0.x); af1[1] = (short)f2bf(c0.y);
            af1[2] = (short)f2bf(c0.z); af1[3] = (short)f2bf(c0.w);
            af1[4] = (short)f2bf(c1.x); af1[5] = (short)f2bf(c1.y);
            af1[6] = (short)f2bf(c1.z); af1[7] = (short)f2bf(c1.w);
#pragma unroll
            for (int t = 0; t < 8; ++t) {
                int col = t * 16 + colbase;
                int boff = (col * 512 + (k0 + kgrp) * 2) ^ ((col & 7) << 4);
                bf16x8 bfrag = *(const bf16x8*)(wl + boff);
                acc0[t] = __builtin_amdgcn_mfma_f32_16x16x32_bf16(af0, bfrag,
                                                                  acc0[t], 0, 0, 0);
                acc1[t] = __builtin_amdgcn_mfma_f32_16x16x32_bf16(af1, bfrag,
                                                                  acc1[t], 0, 0, 0);
            }
        }

        // Wt is dead; reuse its LDS as per-wave transpose tiles
        __syncthreads();
        unsigned short* tl = sm.wt + (size_t)w * (16 * 136);
        int rgrp = (lane >> 4) * 4;
        int row = lane >> 2;
        int c4 = lane & 3;
#pragma unroll
        for (int tilei = 0; tilei < 2; ++tilei) {
            const f32x4* ac = tilei ? acc1 : acc0;
#pragma unroll
            for (int t = 0; t < 8; ++t)
#pragma unroll
                for (int j = 0; j < 4; ++j)
                    tl[(rgrp + j) * 136 + t * 16 + colbase] = f2bf(ac[t][j]);

            int orow = r0 + tilei * 16 + row;
            if (orow < N_NODES) {
#pragma unroll
                for (int u = 0; u < 4; ++u) {
                    int col0 = u * 32 + c4 * 8;
                    int4 v = *(const int4*)(tl + row * 136 + col0);
                    *(int4*)(supb + (size_t)orow * D_OUT + col0) = v;
                }
            }
        }
    }
}

// ---------------------------------------------------------------------------
// scanB: per bin, exclusive prefix over the 391 block-counts.
// One wave per bin (8 bins per 512-thr block). No barriers, no atomics.
// ---------------------------------------------------------------------------
__global__ __launch_bounds__(512) void scanB_kernel(
        const int* __restrict__ counts,
        int* __restrict__ starts,
        int* __restrict__ totals) {
    int wv = threadIdx.x >> 6, lane = threadIdx.x & 63;
    int bin = blockIdx.x * 8 + wv;
    if (bin >= NB) return;
    int carry = 0;
#pragma unroll
    for (int g = 0; g < 7; ++g) {               // ceil(391/64) = 7
        int idx = g * 64 + lane;                // block index
        int v = (idx < NCHUNK) ? counts[(size_t)idx * NB + bin] : 0;
        int s = v;
#pragma unroll
        for (int d = 1; d < 64; d <<= 1) {
            int u = __shfl_up(s, d, 64);
            if (lane >= d) s += u;
        }
        if (idx < NCHUNK) starts[(size_t)idx * NB + bin] = carry + s - v;
        carry += __shfl(s, 63, 64);
    }
    if (lane == 0) totals[bin] = carry;
}

// ---------------------------------------------------------------------------
// flushC: reload edges, seed LDS cursors with global per-(block,bin) starts,
// direct-store tuples to stg. Unique slots -> zero global atomics.
// Tuple: {src | dloc<<17, w_bits}, dloc = dst & 127.
// ---------------------------------------------------------------------------
__global__ __launch_bounds__(512) void flushC_kernel(
        const int* __restrict__ src,
        const int* __restrict__ dst,
        const float* __restrict__ ew,
        const int* __restrict__ starts,
        int2* __restrict__ stg) {
    __shared__ int cur[NB];
    int tid = threadIdx.x;
    int e0 = blockIdx.x * CHUNK;

    const int* srow = starts + (size_t)blockIdx.x * NB;
    for (int i = tid; i < NB; i += 512) cur[i] = srow[i];
    __syncthreads();

#pragma unroll
    for (int k = 0; k < 8; ++k) {
        int e = e0 + k * 512 + tid;
        if (e < N_EDGES) {
            int d = dst[e];
            int bin = d >> 7;
            int pos = atomicAdd(&cur[bin], 1);
            if (pos < REGION)
                stg[(size_t)bin * REGION + pos] =
                    make_int2(src[e] | ((d & 127) << 17), __float_as_int(ew[e]));
        }
    }
}

// ---------------------------------------------------------------------------
// sgather: one block (512 thr) per 128-node bin (782 blocks).
//  A: stash tuples in regs + histogram dloc (128 keys)
//  B: exclusive scan -> base/cursor
//  C: scatter from regs into sorted[] (node-grouped, LDS)
//  D: 8 waves x 16 nodes, register accumulate (lane = 2 ch), 4x unroll.
// ---------------------------------------------------------------------------
__global__ __launch_bounds__(512) void sgather_kernel(
        const unsigned short* __restrict__ supb,
        const int2* __restrict__ stg,
        const int* __restrict__ totals,
        const float* __restrict__ b,
        float* __restrict__ out) {
    __shared__ int2 sorted[REGION];          // 19,456 B
    __shared__ int hist2[NPB];
    __shared__ int base2[NPB + 1];
    __shared__ int cur2[NPB];
    __shared__ int scanbuf[512];

    int tid = threadIdx.x;
    int bkt = blockIdx.x;
    int node0 = bkt * NPB;

    if (tid < NPB) hist2[tid] = 0;
    __syncthreads();

    int cnt = totals[bkt];
    if (cnt > REGION) cnt = REGION;
    const int2* sg = stg + (size_t)bkt * REGION;

    int2 tp[5];
    int dl[5];
#pragma unroll
    for (int k = 0; k < 5; ++k) {
        int e = tid + k * 512;
        dl[k] = -1;
        if (e < cnt) {
            tp[k] = sg[e];
            dl[k] = (tp[k].x >> 17) & 127;
            atomicAdd(&hist2[dl[k]], 1);
        }
    }
    __syncthreads();

    int v = (tid < NPB) ? hist2[tid] : 0;
    scanbuf[tid] = v;
    __syncthreads();
    for (int d = 1; d < NPB; d <<= 1) {
        int t = (tid >= d) ? scanbuf[tid - d] : 0;
        __syncthreads();
        scanbuf[tid] += t;
        __syncthreads();
    }
    if (tid < NPB) {
        base2[tid] = scanbuf[tid] - v;
        cur2[tid] = scanbuf[tid] - v;
    }
    if (tid == 0) base2[NPB] = cnt;
    __syncthreads();

#pragma unroll
    for (int k = 0; k < 5; ++k) {
        if (dl[k] >= 0) {
            int pos = atomicAdd(&cur2[dl[k]], 1);
            sorted[pos] = tp[k];
        }
    }
    __syncthreads();

    int wave = tid >> 6, lane = tid & 63;
    float2 bv = ((const float2*)b)[lane];

#pragma unroll 1
    for (int jj = 0; jj < 16; ++jj) {
        int j = wave * 16 + jj;
        int node = node0 + j;
        if (node >= N_NODES) break;
        int s = base2[j], t = base2[j + 1];
        float ax = 0.f, ay = 0.f;
        int e = s;
        for (; e + 3 < t; e += 4) {
            int2 t0 = sorted[e];
            int2 t1 = sorted[e + 1];
            int2 t2 = sorted[e + 2];
            int2 t3 = sorted[e + 3];
            unsigned p0 = *(const unsigned*)(supb + (size_t)(t0.x & 0x1FFFF) * D_OUT + 2 * lane);
            unsigned p1 = *(const unsigned*)(supb + (size_t)(t1.x & 0x1FFFF) * D_OUT + 2 * lane);
            unsigned p2 = *(const unsigned*)(supb + (size_t)(t2.x & 0x1FFFF) * D_OUT + 2 * lane);
            unsigned p3 = *(const unsigned*)(supb + (size_t)(t3.x & 0x1FFFF) * D_OUT + 2 * lane);
            float w0 = __int_as_float(t0.y);
            float w1 = __int_as_float(t1.y);
            float w2 = __int_as_float(t2.y);
            float w3 = __int_as_float(t3.y);
            ax += w0 * bflo(p0) + w1 * bflo(p1) + w2 * bflo(p2) + w3 * bflo(p3);
            ay += w0 * bfhi(p0) + w1 * bfhi(p1) + w2 * bfhi(p2) + w3 * bfhi(p3);
        }
        for (; e < t; ++e) {
            int2 t0 = sorted[e];
            unsigned p0 = *(const unsigned*)(supb + (size_t)(t0.x & 0x1FFFF) * D_OUT + 2 * lane);
            float w0 = __int_as_float(t0.y);
            ax += w0 * bflo(p0);
            ay += w0 * bfhi(p0);
        }
        ((float2*)(out + (size_t)node * D_OUT))[lane] =
            make_float2(ax + bv.x, ay + bv.y);
    }
}

// ---------------------------------------------------------------------------
extern "C" void kernel_launch(void* const* d_in, const int* in_sizes, int n_in,
                              void* d_out, int out_size, void* d_ws, size_t ws_size,
                              hipStream_t stream) {
    const float* x   = (const float*)d_in[0];
    const int* esrc  = (const int*)d_in[1];
    const int* edst  = (const int*)d_in[2];
    const float* ew  = (const float*)d_in[3];
    const float* W   = (const float*)d_in[4];
    const float* b   = (const float*)d_in[5];
    float* out = (float*)d_out;

    // workspace layout (~43.4 MB)
    uint8_t* w8 = (uint8_t*)d_ws;
    unsigned short* supb = (unsigned short*)w8;               // 25,600,000 B
    int2* stg    = (int2*)(w8 + 25600000);                    // 15,214,592 B (782*2432*8)
    int* counts  = (int*)(w8 + 40814592);                     //  1,223,048 B (391*782*4)
    int* starts  = (int*)(w8 + 42037640);                     //  1,223,048 B
    int* totals  = (int*)(w8 + 43260688);                     //      3,128 B
    unsigned short* Wt = (unsigned short*)(w8 + 43264000);    //     65,536 B

    prep_kernel<<<(D_OUT * D_IN + 255) / 256, 256, 0, stream>>>(W, Wt);

    fusedA_kernel<<<NCHUNK + GEMM_BLOCKS, 256, 0, stream>>>(
        x, Wt, supb, edst, counts);

    scanB_kernel<<<(NB + 7) / 8, 512, 0, stream>>>(counts, starts, totals);

    flushC_kernel<<<NCHUNK, 512, 0, stream>>>(esrc, edst, ew, starts, stg);

    sgather_kernel<<<NB, 512, 0, stream>>>(supb, stg, totals, b, out);
}